// Round 1
// baseline (460.180 us; speedup 1.0000x reference)
//
#include <hip/hip_runtime.h>

// ---------------------------------------------------------------------------
// MultiHeadAttention fused pipeline for MI355X (gfx950)
// x[B,S,E] @ w_qkv -> split QKV -> RoPE -> causal GQA flash attention -> @ w_dense
// B=2 S=2048 E=2048 H=16 KVH=4 D=128
// All matmuls via v_mfma_f32_16x16x32_bf16 (fp32 accumulate).
// Verified fragment layouts (learn_hip m89/m91/m120):
//   C/D: col=lane&15, row=(lane>>4)*4+reg
//   A:   A[m=lane&15][k=(lane>>4)*8+j]
//   B:   B[k=(lane>>4)*8+j][n=lane&15]
// ---------------------------------------------------------------------------

typedef __attribute__((ext_vector_type(8))) short short8;
typedef __attribute__((ext_vector_type(4))) float floatx4;
typedef __attribute__((ext_vector_type(4))) unsigned short ushort4v;

constexpr int NH    = 16;
constexpr int NKV   = 4;
constexpr int HD    = 128;
constexpr int SEQ   = 2048;
constexpr int EMB   = 2048;
constexpr int NBATCH = 2;
constexpr int MROWS = NBATCH * SEQ;          // 4096
constexpr int NQKV  = (NH + 2 * NKV) * HD;   // 3072

__device__ __forceinline__ unsigned short f2b(float f) {
  union { float f; unsigned u; } v; v.f = f;
  unsigned u = v.u + 0x7FFFu + ((v.u >> 16) & 1u);   // RNE
  return (unsigned short)(u >> 16);
}
__device__ __forceinline__ float b2f(unsigned short h) {
  union { unsigned u; float f; } v; v.u = (unsigned)h << 16;
  return v.f;
}

// --------------------------- fp32 -> bf16 cast ------------------------------
__global__ void cvt_f32_bf16(const float* __restrict__ in,
                             unsigned short* __restrict__ out, int n) {
  int i = (blockIdx.x * 256 + threadIdx.x) * 4;
  if (i + 3 < n) {
    floatx4 v = *(const floatx4*)(in + i);
    ushort4v o = { f2b(v[0]), f2b(v[1]), f2b(v[2]), f2b(v[3]) };
    *(ushort4v*)(out + i) = o;
  }
}

// -------------------- fp32 [R][C] -> bf16 [C][R] transpose ------------------
__global__ void transpose_cvt_f32(const float* __restrict__ in,
                                  unsigned short* __restrict__ out,
                                  int R, int C) {
  __shared__ float t[32][33];
  int c0 = blockIdx.x * 32, r0 = blockIdx.y * 32;
  int tx = threadIdx.x & 31, ty = threadIdx.x >> 5;  // ty 0..7
#pragma unroll
  for (int i = 0; i < 32; i += 8)
    t[ty + i][tx] = in[(long)(r0 + ty + i) * C + (c0 + tx)];
  __syncthreads();
#pragma unroll
  for (int i = 0; i < 32; i += 8)
    out[(long)(c0 + ty + i) * R + (r0 + tx)] = f2b(t[tx][ty + i]);
}

// -------------------- bf16 [R][C] -> bf16 [C][R] per-matrix -----------------
__global__ void transpose_bf16(const unsigned short* __restrict__ in,
                               unsigned short* __restrict__ out,
                               int R, int C) {
  __shared__ unsigned short t[32][34];
  long base = (long)blockIdx.z * R * C;
  in += base; out += base;
  int c0 = blockIdx.x * 32, r0 = blockIdx.y * 32;
  int tx = threadIdx.x & 31, ty = threadIdx.x >> 5;
#pragma unroll
  for (int i = 0; i < 32; i += 8)
    t[ty + i][tx] = in[(long)(r0 + ty + i) * C + (c0 + tx)];
  __syncthreads();
#pragma unroll
  for (int i = 0; i < 32; i += 8)
    out[(long)(c0 + ty + i) * R + (r0 + tx)] = t[tx][ty + i];
}

// ------------------------------- RoPE (in-place) ----------------------------
// buf: [NBH][SEQ][HD] bf16, NBH*SEQ*64 threads; pair (i, i+64), angle = s*theta^(-2i/128)
__global__ void rope_kernel(unsigned short* __restrict__ buf) {
  int idx = blockIdx.x * 256 + threadIdx.x;
  int i = idx & 63;
  int s = (idx >> 6) & (SEQ - 1);
  int bh = idx >> 17;                       // SEQ*64 = 1<<17
  unsigned short* p = buf + ((long)bh * SEQ + s) * HD;
  // inv_freq = 10000^(-2i/128) = 2^(-2i/128 * log2(10000))
  float e = -(float)i * (2.0f * 13.287712379549449f / 128.0f);
  float ang = (float)s * exp2f(e);
  float sn, c;
  sincosf(ang, &sn, &c);
  float x1 = b2f(p[i]), x2 = b2f(p[i + 64]);
  p[i]      = f2b(x1 * c - x2 * sn);
  p[i + 64] = f2b(x2 * c + x1 * sn);
}

// ------------------------------- GEMM (B^T) ---------------------------------
// C[M][N] = A[M][K](bf16) * BT[N][K](bf16)^T.  128x128 tile, 4 waves of 64x64.
// MODE 0: scatter bf16 into Q/K/V head-major buffers (qkv projection)
// MODE 1: fp32 dense store to outF (output projection)
constexpr int BM = 128, BN = 128, BK = 64;
constexpr int LDT = BK + 8;   // +16B pad: 2-way (free) LDS conflicts, keeps 16B align

template <int MODE>
__global__ __launch_bounds__(256, 2) void gemm_bt(
    const unsigned short* __restrict__ A,
    const unsigned short* __restrict__ BT,
    int Mdim, int Ndim, int Kdim,
    float* __restrict__ outF,
    unsigned short* __restrict__ Qb,
    unsigned short* __restrict__ Kb,
    unsigned short* __restrict__ Vb) {
  __shared__ __align__(16) unsigned short As[BM][LDT];
  __shared__ __align__(16) unsigned short Bs[BN][LDT];
  const int tid = threadIdx.x;
  const int bm = blockIdx.y * BM;
  const int bn = blockIdx.x * BN;
  const int wave = tid >> 6, lane = tid & 63;
  const int l = lane & 15, q = lane >> 4;
  const int wm = (wave >> 1) * 64, wn = (wave & 1) * 64;

  floatx4 acc[4][4] = {};

  const int sr = tid >> 3;         // 0..31
  const int sc = (tid & 7) * 8;    // 0..56
  const unsigned short* Arow = A + (long)bm * Kdim;
  const unsigned short* Brow = BT + (long)bn * Kdim;

  for (int k0 = 0; k0 < Kdim; k0 += BK) {
#pragma unroll
    for (int r = sr; r < BM; r += 32) {
      *(short8*)&As[r][sc] = *(const short8*)(Arow + (long)r * Kdim + k0 + sc);
      *(short8*)&Bs[r][sc] = *(const short8*)(Brow + (long)r * Kdim + k0 + sc);
    }
    __syncthreads();
#pragma unroll
    for (int kk = 0; kk < 2; ++kk) {
      short8 af[4], bfr[4];
#pragma unroll
      for (int mi = 0; mi < 4; ++mi)
        af[mi] = *(const short8*)&As[wm + mi * 16 + l][kk * 32 + q * 8];
#pragma unroll
      for (int ni = 0; ni < 4; ++ni)
        bfr[ni] = *(const short8*)&Bs[wn + ni * 16 + l][kk * 32 + q * 8];
#pragma unroll
      for (int mi = 0; mi < 4; ++mi)
#pragma unroll
        for (int ni = 0; ni < 4; ++ni)
          acc[mi][ni] = __builtin_amdgcn_mfma_f32_16x16x32_bf16(
              af[mi], bfr[ni], acc[mi][ni], 0, 0, 0);
    }
    __syncthreads();
  }

#pragma unroll
  for (int mi = 0; mi < 4; ++mi) {
    const int rowbase = bm + wm + mi * 16 + q * 4;
#pragma unroll
    for (int ni = 0; ni < 4; ++ni) {
      const int col = bn + wn + ni * 16 + l;
#pragma unroll
      for (int r = 0; r < 4; ++r) {
        const int m = rowbase + r;
        const float v = acc[mi][ni][r];
        if (MODE == 1) {
          outF[(long)m * Ndim + col] = v;
        } else {
          const int bb = m >> 11, s = m & (SEQ - 1);
          const unsigned short bv = f2b(v);
          if (col < NH * HD) {                       // Q
            int hh = col >> 7, d = col & 127;
            Qb[(((long)(bb * NH + hh)) * SEQ + s) * HD + d] = bv;
          } else if (col < NH * HD + NKV * HD) {     // K
            int c2 = col - NH * HD; int hh = c2 >> 7, d = c2 & 127;
            Kb[(((long)(bb * NKV + hh)) * SEQ + s) * HD + d] = bv;
          } else {                                   // V
            int c2 = col - NH * HD - NKV * HD; int hh = c2 >> 7, d = c2 & 127;
            Vb[(((long)(bb * NKV + hh)) * SEQ + s) * HD + d] = bv;
          }
        }
      }
    }
  }
}

// --------------------------- flash attention --------------------------------
// block = (q-tile of 128) x (head) x (batch); 4 waves, each owns 32 q rows.
// Q frags in registers; K chunk [64][128] and VT chunk [128][64] staged in LDS;
// P goes through LDS (C-layout -> A-layout transform). Online softmax in log2.
__global__ __launch_bounds__(256, 2) void attn_kernel(
    const unsigned short* __restrict__ Q,   // [B][NH][S][D]
    const unsigned short* __restrict__ K,   // [B][NKV][S][D]
    const unsigned short* __restrict__ VT,  // [B][NKV][D][S]
    unsigned short* __restrict__ attn) {    // [B*S][NH*D]
  const int qt = blockIdx.x, h = blockIdx.y, b = blockIdx.z;
  const int kvh = h >> 2;   // jnp.repeat: q head h uses kv head h/4
  const int tid = threadIdx.x;
  const int wave = tid >> 6, lane = tid & 63;
  const int l = lane & 15, q = lane >> 4;
  const int wq = wave * 32;

  const unsigned short* Qh = Q + (((long)(b * NH + h)) * SEQ + qt * 128) * HD;
  const unsigned short* Kh = K + ((long)(b * NKV + kvh)) * SEQ * HD;
  const unsigned short* VTh = VT + ((long)(b * NKV + kvh)) * HD * SEQ;

  __shared__ __align__(16) unsigned short Ks[64][136];    // [kv][d], +8 pad
  __shared__ __align__(16) unsigned short VTs[128][72];   // [d][kv], +8 pad
  __shared__ __align__(16) unsigned short Ps[128][72];    // [q][kv], per-wave rows

  short8 qf[2][4];
#pragma unroll
  for (int mi = 0; mi < 2; ++mi)
#pragma unroll
    for (int kk = 0; kk < 4; ++kk)
      qf[mi][kk] = *(const short8*)(Qh + (long)(wq + mi * 16 + l) * HD + kk * 32 + q * 8);

  floatx4 o[2][8] = {};
  float mrow[2][4], lrow[2][4];
#pragma unroll
  for (int mi = 0; mi < 2; ++mi)
#pragma unroll
    for (int r = 0; r < 4; ++r) { mrow[mi][r] = -3e38f; lrow[mi][r] = 0.f; }

  const float sc_l2e = 0.08838834764831845f * 1.4426950408889634f; // 1/sqrt(128)*log2e
  const int nchunk = 2 * qt + 2;   // causal: kv <= qt*128+127

  for (int c = 0; c < nchunk; ++c) {
    const int kv0 = c * 64;
    {
      const int r = tid >> 4, col = (tid & 15) * 8;
#pragma unroll
      for (int rr = r; rr < 64; rr += 16)
        *(short8*)&Ks[rr][col] = *(const short8*)(Kh + (long)(kv0 + rr) * HD + col);
      const int r2 = tid >> 3, col2 = (tid & 7) * 8;
#pragma unroll
      for (int rr = r2; rr < 128; rr += 32)
        *(short8*)&VTs[rr][col2] = *(const short8*)(VTh + (long)rr * SEQ + kv0 + col2);
    }
    __syncthreads();

    // S = Q K^T  (per wave: 32q x 64kv)
    floatx4 sf[2][4] = {};
#pragma unroll
    for (int kk = 0; kk < 4; ++kk) {
      short8 kf[4];
#pragma unroll
      for (int ni = 0; ni < 4; ++ni)
        kf[ni] = *(const short8*)&Ks[ni * 16 + l][kk * 32 + q * 8];
#pragma unroll
      for (int mi = 0; mi < 2; ++mi)
#pragma unroll
        for (int ni = 0; ni < 4; ++ni)
          sf[mi][ni] = __builtin_amdgcn_mfma_f32_16x16x32_bf16(
              qf[mi][kk], kf[ni], sf[mi][ni], 0, 0, 0);
    }

    const bool need_mask = (c >= nchunk - 2);   // only diagonal-adjacent chunks
#pragma unroll
    for (int mi = 0; mi < 2; ++mi) {
#pragma unroll
      for (int r = 0; r < 4; ++r) {
        const int qrow = qt * 128 + wq + mi * 16 + q * 4 + r;
        float smax = -3e38f;
#pragma unroll
        for (int ni = 0; ni < 4; ++ni) {
          float v = sf[mi][ni][r] * sc_l2e;
          if (need_mask && (kv0 + ni * 16 + l > qrow)) v = -3e38f;
          sf[mi][ni][r] = v;
          smax = fmaxf(smax, v);
        }
#pragma unroll
        for (int d = 1; d < 16; d <<= 1) smax = fmaxf(smax, __shfl_xor(smax, d));
        const float mnew = fmaxf(mrow[mi][r], smax);
        const float alpha = exp2f(mrow[mi][r] - mnew);
        mrow[mi][r] = mnew;
        float rsum = 0.f;
#pragma unroll
        for (int ni = 0; ni < 4; ++ni) {
          float p = exp2f(sf[mi][ni][r] - mnew);
          sf[mi][ni][r] = p;
          rsum += p;
        }
#pragma unroll
        for (int d = 1; d < 16; d <<= 1) rsum += __shfl_xor(rsum, d);
        lrow[mi][r] = lrow[mi][r] * alpha + rsum;
#pragma unroll
        for (int di = 0; di < 8; ++di) o[mi][di][r] *= alpha;
#pragma unroll
        for (int ni = 0; ni < 4; ++ni)   // C-layout -> LDS (A-layout source)
          Ps[wq + mi * 16 + q * 4 + r][ni * 16 + l] = f2b(sf[mi][ni][r]);
      }
    }

    // O += P V   (DS ops same-wave in-order: no barrier needed for Ps)
#pragma unroll
    for (int kvk = 0; kvk < 2; ++kvk) {
      short8 pf[2];
#pragma unroll
      for (int mi = 0; mi < 2; ++mi)
        pf[mi] = *(const short8*)&Ps[wq + mi * 16 + l][kvk * 32 + q * 8];
#pragma unroll
      for (int di = 0; di < 8; ++di) {
        short8 vf = *(const short8*)&VTs[di * 16 + l][kvk * 32 + q * 8];
#pragma unroll
        for (int mi = 0; mi < 2; ++mi)
          o[mi][di] = __builtin_amdgcn_mfma_f32_16x16x32_bf16(
              pf[mi], vf, o[mi][di], 0, 0, 0);
      }
    }
    __syncthreads();   // protect Ks/VTs for next chunk
  }

#pragma unroll
  for (int mi = 0; mi < 2; ++mi) {
#pragma unroll
    for (int r = 0; r < 4; ++r) {
      const float inv = 1.0f / lrow[mi][r];
      const int s = qt * 128 + wq + mi * 16 + q * 4 + r;
      unsigned short* dst = attn + ((long)(b * SEQ + s)) * (NH * HD) + h * HD;
#pragma unroll
      for (int di = 0; di < 8; ++di)
        dst[di * 16 + l] = f2b(o[mi][di][r] * inv);
    }
  }
}

// ---------------------------------------------------------------------------
extern "C" void kernel_launch(void* const* d_in, const int* in_sizes, int n_in,
                              void* d_out, int out_size, void* d_ws, size_t ws_size,
                              hipStream_t stream) {
  const float* x       = (const float*)d_in[0];   // [2,2048,2048]
  const float* w_qkv   = (const float*)d_in[1];   // [2048,3072]
  const float* w_dense = (const float*)d_in[2];   // [2048,2048]
  float* out = (float*)d_out;                     // [2,2048,2048] fp32

  char* ws = (char*)d_ws;
  const size_t MB = 1024 * 1024;
  unsigned short* xb    = (unsigned short*)(ws);            // 16 MB: x bf16 (later aliased as attn)
  unsigned short* wqkvT = (unsigned short*)(ws + 16 * MB);  // 12 MB
  unsigned short* wdT   = (unsigned short*)(ws + 28 * MB);  //  8 MB
  unsigned short* Qb    = (unsigned short*)(ws + 36 * MB);  // 16 MB
  unsigned short* Kb    = (unsigned short*)(ws + 52 * MB);  //  4 MB
  unsigned short* Vb    = (unsigned short*)(ws + 56 * MB);  //  4 MB
  unsigned short* VTb   = (unsigned short*)(ws + 60 * MB);  //  4 MB   (total 64 MB)
  unsigned short* attn  = xb;   // x no longer needed after qkv GEMM

  cvt_f32_bf16<<<(MROWS * EMB) / (256 * 4), 256, 0, stream>>>(x, xb, MROWS * EMB);
  transpose_cvt_f32<<<dim3(NQKV / 32, EMB / 32), 256, 0, stream>>>(w_qkv, wqkvT, EMB, NQKV);
  transpose_cvt_f32<<<dim3(EMB / 32, (NH * HD) / 32), 256, 0, stream>>>(w_dense, wdT, NH * HD, EMB);

  gemm_bt<0><<<dim3(NQKV / BN, MROWS / BM), 256, 0, stream>>>(
      xb, wqkvT, MROWS, NQKV, EMB, nullptr, Qb, Kb, Vb);

  rope_kernel<<<(NBATCH * NH * SEQ * 64) / 256, 256, 0, stream>>>(Qb);
  rope_kernel<<<(NBATCH * NKV * SEQ * 64) / 256, 256, 0, stream>>>(Kb);

  transpose_bf16<<<dim3(HD / 32, SEQ / 32, NBATCH * NKV), 256, 0, stream>>>(Vb, VTb, SEQ, HD);

  attn_kernel<<<dim3(SEQ / 128, NH, NBATCH), 256, 0, stream>>>(Qb, Kb, VTb, attn);

  gemm_bt<1><<<dim3(EMB / BN, MROWS / BM), 256, 0, stream>>>(
      attn, wdT, MROWS, EMB, NH * HD, out, nullptr, nullptr, nullptr);
}

// Round 2
// 387.383 us; speedup vs baseline: 1.1879x; 1.1879x over previous
//
#include <hip/hip_runtime.h>

// ---------------------------------------------------------------------------
// MultiHeadAttention fused pipeline for MI355X (gfx950)
// x[B,S,E] @ w_qkv -> split QKV -> RoPE -> causal GQA flash attention -> @ w_dense
// B=2 S=2048 E=2048 H=16 KVH=4 D=128
// R2: (1) attn: paired q-tiles (qt, 31-qt) of 64 rows -> uniform 33 chunks/block
//     (2) gemm: m97-style global_load_lds width-16 staging, unpadded LDS
// ---------------------------------------------------------------------------

typedef __attribute__((ext_vector_type(8))) short short8;
typedef __attribute__((ext_vector_type(4))) float floatx4;
typedef __attribute__((ext_vector_type(4))) unsigned short ushort4v;

constexpr int NH    = 16;
constexpr int NKV   = 4;
constexpr int HD    = 128;
constexpr int SEQ   = 2048;
constexpr int EMB   = 2048;
constexpr int NBATCH = 2;
constexpr int MROWS = NBATCH * SEQ;          // 4096
constexpr int NQKV  = (NH + 2 * NKV) * HD;   // 3072

__device__ __forceinline__ unsigned short f2b(float f) {
  union { float f; unsigned u; } v; v.f = f;
  unsigned u = v.u + 0x7FFFu + ((v.u >> 16) & 1u);   // RNE
  return (unsigned short)(u >> 16);
}
__device__ __forceinline__ float b2f(unsigned short h) {
  union { unsigned u; float f; } v; v.u = (unsigned)h << 16;
  return v.f;
}

// async global->LDS DMA, 16B per lane; lds dest = uniform base + lane*16
__device__ __forceinline__ void gload_lds16(const unsigned short* g,
                                            unsigned short* lds) {
  __builtin_amdgcn_global_load_lds(
      (const __attribute__((address_space(1))) unsigned int*)g,
      (__attribute__((address_space(3))) unsigned int*)lds, 16, 0, 0);
}

// --------------------------- fp32 -> bf16 cast ------------------------------
__global__ void cvt_f32_bf16(const float* __restrict__ in,
                             unsigned short* __restrict__ out, int n) {
  int i = (blockIdx.x * 256 + threadIdx.x) * 4;
  if (i + 3 < n) {
    floatx4 v = *(const floatx4*)(in + i);
    ushort4v o = { f2b(v[0]), f2b(v[1]), f2b(v[2]), f2b(v[3]) };
    *(ushort4v*)(out + i) = o;
  }
}

// -------------------- fp32 [R][C] -> bf16 [C][R] transpose ------------------
__global__ void transpose_cvt_f32(const float* __restrict__ in,
                                  unsigned short* __restrict__ out,
                                  int R, int C) {
  __shared__ float t[32][33];
  int c0 = blockIdx.x * 32, r0 = blockIdx.y * 32;
  int tx = threadIdx.x & 31, ty = threadIdx.x >> 5;  // ty 0..7
#pragma unroll
  for (int i = 0; i < 32; i += 8)
    t[ty + i][tx] = in[(long)(r0 + ty + i) * C + (c0 + tx)];
  __syncthreads();
#pragma unroll
  for (int i = 0; i < 32; i += 8)
    out[(long)(c0 + ty + i) * R + (r0 + tx)] = f2b(t[tx][ty + i]);
}

// -------------------- bf16 [R][C] -> bf16 [C][R] per-matrix -----------------
__global__ void transpose_bf16(const unsigned short* __restrict__ in,
                               unsigned short* __restrict__ out,
                               int R, int C) {
  __shared__ unsigned short t[32][34];
  long base = (long)blockIdx.z * R * C;
  in += base; out += base;
  int c0 = blockIdx.x * 32, r0 = blockIdx.y * 32;
  int tx = threadIdx.x & 31, ty = threadIdx.x >> 5;
#pragma unroll
  for (int i = 0; i < 32; i += 8)
    t[ty + i][tx] = in[(long)(r0 + ty + i) * C + (c0 + tx)];
  __syncthreads();
#pragma unroll
  for (int i = 0; i < 32; i += 8)
    out[(long)(c0 + ty + i) * R + (r0 + tx)] = t[tx][ty + i];
}

// ------------------------------- RoPE (in-place) ----------------------------
__global__ void rope_kernel(unsigned short* __restrict__ buf) {
  int idx = blockIdx.x * 256 + threadIdx.x;
  int i = idx & 63;
  int s = (idx >> 6) & (SEQ - 1);
  int bh = idx >> 17;                       // SEQ*64 = 1<<17
  unsigned short* p = buf + ((long)bh * SEQ + s) * HD;
  float e = -(float)i * (2.0f * 13.287712379549449f / 128.0f);
  float ang = (float)s * exp2f(e);
  float sn, c;
  sincosf(ang, &sn, &c);
  float x1 = b2f(p[i]), x2 = b2f(p[i + 64]);
  p[i]      = f2b(x1 * c - x2 * sn);
  p[i + 64] = f2b(x2 * c + x1 * sn);
}

// ------------------------------- GEMM (B^T) ---------------------------------
// C[M][N] = A[M][K](bf16) * BT[N][K](bf16)^T.  128x128 tile, 4 waves of 64x64.
// m97 structure: unpadded LDS, global_load_lds width-16 staging.
// MODE 0: scatter bf16 into Q/K/V head-major buffers; MODE 1: fp32 dense store.
constexpr int BM = 128, BN = 128, BK = 64;

template <int MODE>
__global__ __launch_bounds__(256, 2) void gemm_bt(
    const unsigned short* __restrict__ A,
    const unsigned short* __restrict__ BT,
    int Mdim, int Ndim, int Kdim,
    float* __restrict__ outF,
    unsigned short* __restrict__ Qb,
    unsigned short* __restrict__ Kb,
    unsigned short* __restrict__ Vb) {
  __shared__ __align__(16) unsigned short As[BM][BK];   // 16 KB
  __shared__ __align__(16) unsigned short Bs[BN][BK];   // 16 KB
  const int tid = threadIdx.x;
  const int bm = blockIdx.y * BM;
  const int bn = blockIdx.x * BN;
  const int wave = tid >> 6, lane = tid & 63;
  const int l = lane & 15, q = lane >> 4;
  const int wm = (wave >> 1) * 64, wn = (wave & 1) * 64;

  floatx4 acc[4][4] = {};

  // DMA staging: one issue = 64 lanes x 16B = 1KB = 8 rows of 64 shorts.
  const int srow = lane >> 3;        // 0..7
  const int scol = (lane & 7) * 8;   // 0..56 shorts
  const unsigned short* Arow = A + (long)bm * Kdim;
  const unsigned short* Brow = BT + (long)bn * Kdim;

  for (int k0 = 0; k0 < Kdim; k0 += BK) {
#pragma unroll
    for (int i = 0; i < 4; ++i) {
      const int r0 = wave * 32 + i * 8;
      gload_lds16(Arow + (long)(r0 + srow) * Kdim + k0 + scol, &As[r0][0]);
      gload_lds16(Brow + (long)(r0 + srow) * Kdim + k0 + scol, &Bs[r0][0]);
    }
    __syncthreads();
#pragma unroll
    for (int kk = 0; kk < 2; ++kk) {
      short8 af[4], bfr[4];
#pragma unroll
      for (int mi = 0; mi < 4; ++mi)
        af[mi] = *(const short8*)&As[wm + mi * 16 + l][kk * 32 + q * 8];
#pragma unroll
      for (int ni = 0; ni < 4; ++ni)
        bfr[ni] = *(const short8*)&Bs[wn + ni * 16 + l][kk * 32 + q * 8];
#pragma unroll
      for (int mi = 0; mi < 4; ++mi)
#pragma unroll
        for (int ni = 0; ni < 4; ++ni)
          acc[mi][ni] = __builtin_amdgcn_mfma_f32_16x16x32_bf16(
              af[mi], bfr[ni], acc[mi][ni], 0, 0, 0);
    }
    __syncthreads();
  }

#pragma unroll
  for (int mi = 0; mi < 4; ++mi) {
    const int rowbase = bm + wm + mi * 16 + q * 4;
#pragma unroll
    for (int ni = 0; ni < 4; ++ni) {
      const int col = bn + wn + ni * 16 + l;
#pragma unroll
      for (int r = 0; r < 4; ++r) {
        const int m = rowbase + r;
        const float v = acc[mi][ni][r];
        if (MODE == 1) {
          outF[(long)m * Ndim + col] = v;
        } else {
          const int bb = m >> 11, s = m & (SEQ - 1);
          const unsigned short bv = f2b(v);
          if (col < NH * HD) {                       // Q
            int hh = col >> 7, d = col & 127;
            Qb[(((long)(bb * NH + hh)) * SEQ + s) * HD + d] = bv;
          } else if (col < NH * HD + NKV * HD) {     // K
            int c2 = col - NH * HD; int hh = c2 >> 7, d = c2 & 127;
            Kb[(((long)(bb * NKV + hh)) * SEQ + s) * HD + d] = bv;
          } else {                                   // V
            int c2 = col - NH * HD - NKV * HD; int hh = c2 >> 7, d = c2 & 127;
            Vb[(((long)(bb * NKV + hh)) * SEQ + s) * HD + d] = bv;
          }
        }
      }
    }
  }
}

// --------------------------- flash attention --------------------------------
// R2: q-tile = 64 rows (4 waves x 16 rows). Block processes tile pair
// (pair, 31-pair): nchunk = (pair+1) + (32-pair) = 33, uniform across grid.
__global__ __launch_bounds__(256, 2) void attn_kernel(
    const unsigned short* __restrict__ Q,   // [B][NH][S][D]
    const unsigned short* __restrict__ K,   // [B][NKV][S][D]
    const unsigned short* __restrict__ VT,  // [B][NKV][D][S]
    unsigned short* __restrict__ attn) {    // [B*S][NH*D]
  const int pair = blockIdx.x, h = blockIdx.y, b = blockIdx.z;
  const int kvh = h >> 2;   // jnp.repeat: q head h uses kv head h/4
  const int tid = threadIdx.x;
  const int wave = tid >> 6, lane = tid & 63;
  const int l = lane & 15, q = lane >> 4;
  const int wq = wave * 16;

  const unsigned short* Kh = K + ((long)(b * NKV + kvh)) * SEQ * HD;
  const unsigned short* VTh = VT + ((long)(b * NKV + kvh)) * HD * SEQ;

  __shared__ __align__(16) unsigned short Ks[64][136];    // [kv][d], +8 pad
  __shared__ __align__(16) unsigned short VTs[128][72];   // [d][kv], +8 pad
  __shared__ __align__(16) unsigned short Ps[64][72];     // [q][kv], +8 pad

  const float sc_l2e = 0.08838834764831845f * 1.4426950408889634f; // 1/sqrt(128)*log2e

#pragma unroll 1
  for (int half = 0; half < 2; ++half) {
    const int qt = half ? (31 - pair) : pair;
    const unsigned short* Qh = Q + (((long)(b * NH + h)) * SEQ + qt * 64) * HD;

    short8 qf[4];
#pragma unroll
    for (int kk = 0; kk < 4; ++kk)
      qf[kk] = *(const short8*)(Qh + (long)(wq + l) * HD + kk * 32 + q * 8);

    floatx4 o[8] = {};
    float mrow[4], lrow[4];
#pragma unroll
    for (int r = 0; r < 4; ++r) { mrow[r] = -3e38f; lrow[r] = 0.f; }

    const int nchunk = qt + 1;   // causal, Tk=64
    for (int c = 0; c < nchunk; ++c) {
      const int kv0 = c * 64;
      {
        const int r = tid >> 4, col = (tid & 15) * 8;
#pragma unroll
        for (int rr = r; rr < 64; rr += 16)
          *(short8*)&Ks[rr][col] = *(const short8*)(Kh + (long)(kv0 + rr) * HD + col);
        const int r2 = tid >> 3, col2 = (tid & 7) * 8;
#pragma unroll
        for (int rr = r2; rr < 128; rr += 32)
          *(short8*)&VTs[rr][col2] = *(const short8*)(VTh + (long)rr * SEQ + kv0 + col2);
      }
      __syncthreads();

      // S = Q K^T  (per wave: 16q x 64kv)
      floatx4 sf[4] = {};
#pragma unroll
      for (int kk = 0; kk < 4; ++kk) {
        short8 kf[4];
#pragma unroll
        for (int ni = 0; ni < 4; ++ni)
          kf[ni] = *(const short8*)&Ks[ni * 16 + l][kk * 32 + q * 8];
#pragma unroll
        for (int ni = 0; ni < 4; ++ni)
          sf[ni] = __builtin_amdgcn_mfma_f32_16x16x32_bf16(
              qf[kk], kf[ni], sf[ni], 0, 0, 0);
      }

      const bool need_mask = (c == nchunk - 1);   // only the diagonal chunk
#pragma unroll
      for (int r = 0; r < 4; ++r) {
        const int qrow = qt * 64 + wq + q * 4 + r;
        float smax = -3e38f;
#pragma unroll
        for (int ni = 0; ni < 4; ++ni) {
          float v = sf[ni][r] * sc_l2e;
          if (need_mask && (kv0 + ni * 16 + l > qrow)) v = -3e38f;
          sf[ni][r] = v;
          smax = fmaxf(smax, v);
        }
#pragma unroll
        for (int d = 1; d < 16; d <<= 1) smax = fmaxf(smax, __shfl_xor(smax, d));
        const float mnew = fmaxf(mrow[r], smax);
        const float alpha = exp2f(mrow[r] - mnew);
        mrow[r] = mnew;
        float rsum = 0.f;
#pragma unroll
        for (int ni = 0; ni < 4; ++ni) {
          float p = exp2f(sf[ni][r] - mnew);
          sf[ni][r] = p;
          rsum += p;
        }
#pragma unroll
        for (int d = 1; d < 16; d <<= 1) rsum += __shfl_xor(rsum, d);
        lrow[r] = lrow[r] * alpha + rsum;
#pragma unroll
        for (int di = 0; di < 8; ++di) o[di][r] *= alpha;
#pragma unroll
        for (int ni = 0; ni < 4; ++ni)   // C-layout -> LDS (A-layout source)
          Ps[wq + q * 4 + r][ni * 16 + l] = f2b(sf[ni][r]);
      }

      // O += P V   (Ps write->read same wave: DS in-order, no barrier)
#pragma unroll
      for (int kvk = 0; kvk < 2; ++kvk) {
        short8 pf = *(const short8*)&Ps[wq + l][kvk * 32 + q * 8];
#pragma unroll
        for (int di = 0; di < 8; ++di) {
          short8 vf = *(const short8*)&VTs[di * 16 + l][kvk * 32 + q * 8];
          o[di] = __builtin_amdgcn_mfma_f32_16x16x32_bf16(pf, vf, o[di], 0, 0, 0);
        }
      }
      __syncthreads();   // protect Ks/VTs for next chunk
    }

#pragma unroll
    for (int r = 0; r < 4; ++r) {
      const float inv = 1.0f / lrow[r];
      const int s = qt * 64 + wq + q * 4 + r;
      unsigned short* dst = attn + ((long)(b * SEQ + s)) * (NH * HD) + h * HD;
#pragma unroll
      for (int di = 0; di < 8; ++di)
        dst[di * 16 + l] = f2b(o[di][r] * inv);
    }
  }
}

// ---------------------------------------------------------------------------
extern "C" void kernel_launch(void* const* d_in, const int* in_sizes, int n_in,
                              void* d_out, int out_size, void* d_ws, size_t ws_size,
                              hipStream_t stream) {
  const float* x       = (const float*)d_in[0];   // [2,2048,2048]
  const float* w_qkv   = (const float*)d_in[1];   // [2048,3072]
  const float* w_dense = (const float*)d_in[2];   // [2048,2048]
  float* out = (float*)d_out;                     // [2,2048,2048] fp32

  char* ws = (char*)d_ws;
  const size_t MB = 1024 * 1024;
  unsigned short* xb    = (unsigned short*)(ws);            // 16 MB (aliased as attn later)
  unsigned short* wqkvT = (unsigned short*)(ws + 16 * MB);  // 12 MB
  unsigned short* wdT   = (unsigned short*)(ws + 28 * MB);  //  8 MB
  unsigned short* Qb    = (unsigned short*)(ws + 36 * MB);  // 16 MB
  unsigned short* Kb    = (unsigned short*)(ws + 52 * MB);  //  4 MB
  unsigned short* Vb    = (unsigned short*)(ws + 56 * MB);  //  4 MB
  unsigned short* VTb   = (unsigned short*)(ws + 60 * MB);  //  4 MB   (total 64 MB)
  unsigned short* attn  = xb;   // x no longer needed after qkv GEMM

  cvt_f32_bf16<<<(MROWS * EMB) / (256 * 4), 256, 0, stream>>>(x, xb, MROWS * EMB);
  transpose_cvt_f32<<<dim3(NQKV / 32, EMB / 32), 256, 0, stream>>>(w_qkv, wqkvT, EMB, NQKV);
  transpose_cvt_f32<<<dim3(EMB / 32, (NH * HD) / 32), 256, 0, stream>>>(w_dense, wdT, NH * HD, EMB);

  gemm_bt<0><<<dim3(NQKV / BN, MROWS / BM), 256, 0, stream>>>(
      xb, wqkvT, MROWS, NQKV, EMB, nullptr, Qb, Kb, Vb);

  rope_kernel<<<(NBATCH * NH * SEQ * 64) / 256, 256, 0, stream>>>(Qb);
  rope_kernel<<<(NBATCH * NKV * SEQ * 64) / 256, 256, 0, stream>>>(Kb);

  transpose_bf16<<<dim3(HD / 32, SEQ / 32, NBATCH * NKV), 256, 0, stream>>>(Vb, VTb, SEQ, HD);

  attn_kernel<<<dim3(16, NH, NBATCH), 256, 0, stream>>>(Qb, Kb, VTb, attn);

  gemm_bt<1><<<dim3(EMB / BN, MROWS / BM), 256, 0, stream>>>(
      attn, wdT, MROWS, EMB, NH * HD, out, nullptr, nullptr, nullptr);
}

// Round 3
// 336.506 us; speedup vs baseline: 1.3675x; 1.1512x over previous
//
#include <hip/hip_runtime.h>

// ---------------------------------------------------------------------------
// MultiHeadAttention fused pipeline for MI355X (gfx950)
// x[B,S,E] @ w_qkv -> split QKV -> RoPE -> causal GQA flash attention -> @ w_dense
// B=2 S=2048 E=2048 H=16 KVH=4 D=128
// R3: attn restructured as a double-buffered async pipeline:
//     global_load_lds width-16 staging of K/VT with XOR-swizzled source
//     addressing (conflict-reduced unpadded LDS), prefetch chunk c+1 during
//     compute of chunk c, one barrier per chunk.
// ---------------------------------------------------------------------------

typedef __attribute__((ext_vector_type(8))) short short8;
typedef __attribute__((ext_vector_type(4))) float floatx4;
typedef __attribute__((ext_vector_type(4))) unsigned short ushort4v;

constexpr int NH    = 16;
constexpr int NKV   = 4;
constexpr int HD    = 128;
constexpr int SEQ   = 2048;
constexpr int EMB   = 2048;
constexpr int NBATCH = 2;
constexpr int MROWS = NBATCH * SEQ;          // 4096
constexpr int NQKV  = (NH + 2 * NKV) * HD;   // 3072

__device__ __forceinline__ unsigned short f2b(float f) {
  union { float f; unsigned u; } v; v.f = f;
  unsigned u = v.u + 0x7FFFu + ((v.u >> 16) & 1u);   // RNE
  return (unsigned short)(u >> 16);
}
__device__ __forceinline__ float b2f(unsigned short h) {
  union { unsigned u; float f; } v; v.u = (unsigned)h << 16;
  return v.f;
}

// async global->LDS DMA, 16B per lane; lds dest = uniform base + lane*16
__device__ __forceinline__ void gload_lds16(const unsigned short* g,
                                            unsigned short* lds) {
  __builtin_amdgcn_global_load_lds(
      (const __attribute__((address_space(1))) unsigned int*)g,
      (__attribute__((address_space(3))) unsigned int*)lds, 16, 0, 0);
}

// --------------------------- fp32 -> bf16 cast ------------------------------
__global__ void cvt_f32_bf16(const float* __restrict__ in,
                             unsigned short* __restrict__ out, int n) {
  int i = (blockIdx.x * 256 + threadIdx.x) * 4;
  if (i + 3 < n) {
    floatx4 v = *(const floatx4*)(in + i);
    ushort4v o = { f2b(v[0]), f2b(v[1]), f2b(v[2]), f2b(v[3]) };
    *(ushort4v*)(out + i) = o;
  }
}

// -------------------- fp32 [R][C] -> bf16 [C][R] transpose ------------------
__global__ void transpose_cvt_f32(const float* __restrict__ in,
                                  unsigned short* __restrict__ out,
                                  int R, int C) {
  __shared__ float t[32][33];
  int c0 = blockIdx.x * 32, r0 = blockIdx.y * 32;
  int tx = threadIdx.x & 31, ty = threadIdx.x >> 5;  // ty 0..7
#pragma unroll
  for (int i = 0; i < 32; i += 8)
    t[ty + i][tx] = in[(long)(r0 + ty + i) * C + (c0 + tx)];
  __syncthreads();
#pragma unroll
  for (int i = 0; i < 32; i += 8)
    out[(long)(c0 + ty + i) * R + (r0 + tx)] = f2b(t[tx][ty + i]);
}

// -------------------- bf16 [R][C] -> bf16 [C][R] per-matrix -----------------
__global__ void transpose_bf16(const unsigned short* __restrict__ in,
                               unsigned short* __restrict__ out,
                               int R, int C) {
  __shared__ unsigned short t[32][34];
  long base = (long)blockIdx.z * R * C;
  in += base; out += base;
  int c0 = blockIdx.x * 32, r0 = blockIdx.y * 32;
  int tx = threadIdx.x & 31, ty = threadIdx.x >> 5;
#pragma unroll
  for (int i = 0; i < 32; i += 8)
    t[ty + i][tx] = in[(long)(r0 + ty + i) * C + (c0 + tx)];
  __syncthreads();
#pragma unroll
  for (int i = 0; i < 32; i += 8)
    out[(long)(c0 + ty + i) * R + (r0 + tx)] = t[tx][ty + i];
}

// ------------------------------- RoPE (in-place) ----------------------------
__global__ void rope_kernel(unsigned short* __restrict__ buf) {
  int idx = blockIdx.x * 256 + threadIdx.x;
  int i = idx & 63;
  int s = (idx >> 6) & (SEQ - 1);
  int bh = idx >> 17;                       // SEQ*64 = 1<<17
  unsigned short* p = buf + ((long)bh * SEQ + s) * HD;
  float e = -(float)i * (2.0f * 13.287712379549449f / 128.0f);
  float ang = (float)s * exp2f(e);
  float sn, c;
  sincosf(ang, &sn, &c);
  float x1 = b2f(p[i]), x2 = b2f(p[i + 64]);
  p[i]      = f2b(x1 * c - x2 * sn);
  p[i + 64] = f2b(x2 * c + x1 * sn);
}

// ------------------------------- GEMM (B^T) ---------------------------------
// C[M][N] = A[M][K](bf16) * BT[N][K](bf16)^T.  128x128 tile, 4 waves of 64x64.
// m97 structure: unpadded LDS, global_load_lds width-16 staging.
// MODE 0: scatter bf16 into Q/K/V head-major buffers; MODE 1: fp32 dense store.
constexpr int BM = 128, BN = 128, BK = 64;

template <int MODE>
__global__ __launch_bounds__(256, 2) void gemm_bt(
    const unsigned short* __restrict__ A,
    const unsigned short* __restrict__ BT,
    int Mdim, int Ndim, int Kdim,
    float* __restrict__ outF,
    unsigned short* __restrict__ Qb,
    unsigned short* __restrict__ Kb,
    unsigned short* __restrict__ Vb) {
  __shared__ __align__(16) unsigned short As[BM][BK];   // 16 KB
  __shared__ __align__(16) unsigned short Bs[BN][BK];   // 16 KB
  const int tid = threadIdx.x;
  const int bm = blockIdx.y * BM;
  const int bn = blockIdx.x * BN;
  const int wave = tid >> 6, lane = tid & 63;
  const int l = lane & 15, q = lane >> 4;
  const int wm = (wave >> 1) * 64, wn = (wave & 1) * 64;

  floatx4 acc[4][4] = {};

  // DMA staging: one issue = 64 lanes x 16B = 1KB = 8 rows of 64 shorts.
  const int srow = lane >> 3;        // 0..7
  const int scol = (lane & 7) * 8;   // 0..56 shorts
  const unsigned short* Arow = A + (long)bm * Kdim;
  const unsigned short* Brow = BT + (long)bn * Kdim;

  for (int k0 = 0; k0 < Kdim; k0 += BK) {
#pragma unroll
    for (int i = 0; i < 4; ++i) {
      const int r0 = wave * 32 + i * 8;
      gload_lds16(Arow + (long)(r0 + srow) * Kdim + k0 + scol, &As[r0][0]);
      gload_lds16(Brow + (long)(r0 + srow) * Kdim + k0 + scol, &Bs[r0][0]);
    }
    __syncthreads();
#pragma unroll
    for (int kk = 0; kk < 2; ++kk) {
      short8 af[4], bfr[4];
#pragma unroll
      for (int mi = 0; mi < 4; ++mi)
        af[mi] = *(const short8*)&As[wm + mi * 16 + l][kk * 32 + q * 8];
#pragma unroll
      for (int ni = 0; ni < 4; ++ni)
        bfr[ni] = *(const short8*)&Bs[wn + ni * 16 + l][kk * 32 + q * 8];
#pragma unroll
      for (int mi = 0; mi < 4; ++mi)
#pragma unroll
        for (int ni = 0; ni < 4; ++ni)
          acc[mi][ni] = __builtin_amdgcn_mfma_f32_16x16x32_bf16(
              af[mi], bfr[ni], acc[mi][ni], 0, 0, 0);
    }
    __syncthreads();
  }

#pragma unroll
  for (int mi = 0; mi < 4; ++mi) {
    const int rowbase = bm + wm + mi * 16 + q * 4;
#pragma unroll
    for (int ni = 0; ni < 4; ++ni) {
      const int col = bn + wn + ni * 16 + l;
#pragma unroll
      for (int r = 0; r < 4; ++r) {
        const int m = rowbase + r;
        const float v = acc[mi][ni][r];
        if (MODE == 1) {
          outF[(long)m * Ndim + col] = v;
        } else {
          const int bb = m >> 11, s = m & (SEQ - 1);
          const unsigned short bv = f2b(v);
          if (col < NH * HD) {                       // Q
            int hh = col >> 7, d = col & 127;
            Qb[(((long)(bb * NH + hh)) * SEQ + s) * HD + d] = bv;
          } else if (col < NH * HD + NKV * HD) {     // K
            int c2 = col - NH * HD; int hh = c2 >> 7, d = c2 & 127;
            Kb[(((long)(bb * NKV + hh)) * SEQ + s) * HD + d] = bv;
          } else {                                   // V
            int c2 = col - NH * HD - NKV * HD; int hh = c2 >> 7, d = c2 & 127;
            Vb[(((long)(bb * NKV + hh)) * SEQ + s) * HD + d] = bv;
          }
        }
      }
    }
  }
}

// --------------------------- flash attention --------------------------------
// q-tile = 64 rows (4 waves x 16 rows), paired (pair, 31-pair) -> uniform 33
// chunks/block. K/VT staged by async DMA into double-buffered, XOR-swizzled
// unpadded LDS; prefetch of chunk c+1 overlaps compute of chunk c.
// Swizzle: 16B block at logical (row, bl) lives at physical bp = bl ^ (row&Mask).
__global__ __launch_bounds__(256, 2) void attn_kernel(
    const unsigned short* __restrict__ Q,   // [B][NH][S][D]
    const unsigned short* __restrict__ K,   // [B][NKV][S][D]
    const unsigned short* __restrict__ VT,  // [B][NKV][D][S]
    unsigned short* __restrict__ attn) {    // [B*S][NH*D]
  const int pair = blockIdx.x, h = blockIdx.y, b = blockIdx.z;
  const int kvh = h >> 2;   // jnp.repeat: q head h uses kv head h/4
  const int tid = threadIdx.x;
  const int wave = tid >> 6, lane = tid & 63;
  const int l = lane & 15, q = lane >> 4;
  const int l7 = l & 7;
  const int wq = wave * 16;

  const unsigned short* Kh = K + ((long)(b * NKV + kvh)) * SEQ * HD;
  const unsigned short* VTh = VT + ((long)(b * NKV + kvh)) * HD * SEQ;

  __shared__ __align__(16) unsigned short Ks[2][64 * 128];    // 2x16KB, swizzled (mask 15)
  __shared__ __align__(16) unsigned short VTs[2][128 * 64];   // 2x16KB, swizzled (mask 7)
  __shared__ __align__(16) unsigned short Ps[64][72];         // [q][kv], +8 pad

  // K DMA: issue = 1KB = 4 rows (row = 256B). lane: row=r0+(lane>>4), bp=lane&15,
  // fetches logical block bl = bp ^ (row&15).
  const int k_rl = lane >> 4;          // 0..3
  const int k_bp = lane & 15;
  // VT DMA: issue = 1KB = 8 rows (row = 128B). lane: row=r0+(lane>>3), bp=lane&7,
  // fetches logical block bl = bp ^ (row&7).
  const int v_rl = lane >> 3;          // 0..7
  const int v_bp = lane & 7;

  const float sc_l2e = 0.08838834764831845f * 1.4426950408889634f; // 1/sqrt(128)*log2e

#pragma unroll 1
  for (int half = 0; half < 2; ++half) {
    const int qt = half ? (31 - pair) : pair;
    const unsigned short* Qh = Q + (((long)(b * NH + h)) * SEQ + qt * 64) * HD;

    short8 qf[4];
#pragma unroll
    for (int kk = 0; kk < 4; ++kk)
      qf[kk] = *(const short8*)(Qh + (long)(wq + l) * HD + kk * 32 + q * 8);

    floatx4 o[8] = {};
    float mrow[4], lrow[4];
#pragma unroll
    for (int r = 0; r < 4; ++r) { mrow[r] = -3e38f; lrow[r] = 0.f; }

    const int nchunk = qt + 1;   // causal, Tk=64

    // ---- stage chunk 0 into buffer 0 ----
    {
#pragma unroll
      for (int j = 0; j < 4; ++j) {
        const int r0 = (wave * 4 + j) * 4;
        const int row = r0 + k_rl;
        gload_lds16(Kh + (long)row * HD + (k_bp ^ (row & 15)) * 8,
                    &Ks[0][r0 * 128]);
      }
#pragma unroll
      for (int j = 0; j < 4; ++j) {
        const int r0 = (wave * 4 + j) * 8;
        const int row = r0 + v_rl;
        gload_lds16(VTh + (long)row * SEQ + (v_bp ^ (row & 7)) * 8,
                    &VTs[0][r0 * 64]);
      }
    }
    __syncthreads();   // DMA drained (compiler emits vmcnt(0) before barrier)

#pragma unroll 1
    for (int c = 0; c < nchunk; ++c) {
      const int cur = c & 1;
      // ---- prefetch chunk c+1 into the other buffer (overlaps compute) ----
      if (c + 1 < nchunk) {
        const int kv1 = (c + 1) * 64;
#pragma unroll
        for (int j = 0; j < 4; ++j) {
          const int r0 = (wave * 4 + j) * 4;
          const int row = r0 + k_rl;
          gload_lds16(Kh + (long)(kv1 + row) * HD + (k_bp ^ (row & 15)) * 8,
                      &Ks[cur ^ 1][r0 * 128]);
        }
#pragma unroll
        for (int j = 0; j < 4; ++j) {
          const int r0 = (wave * 4 + j) * 8;
          const int row = r0 + v_rl;
          gload_lds16(VTh + (long)row * SEQ + kv1 + (v_bp ^ (row & 7)) * 8,
                      &VTs[cur ^ 1][r0 * 64]);
        }
      }

      const int kv0 = c * 64;

      // ---- S = Q K^T (per wave: 16q x 64kv) ----
      floatx4 sf[4] = {};
#pragma unroll
      for (int kk = 0; kk < 4; ++kk) {
        short8 kf[4];
#pragma unroll
        for (int ni = 0; ni < 4; ++ni) {
          const int row = ni * 16 + l;
          kf[ni] = *(const short8*)&Ks[cur][row * 128 + (((kk * 4 + q) ^ l) * 8)];
        }
#pragma unroll
        for (int ni = 0; ni < 4; ++ni)
          sf[ni] = __builtin_amdgcn_mfma_f32_16x16x32_bf16(
              qf[kk], kf[ni], sf[ni], 0, 0, 0);
      }

      // ---- online softmax (log2 domain) ----
      const bool need_mask = (c == nchunk - 1);   // only the diagonal chunk
#pragma unroll
      for (int r = 0; r < 4; ++r) {
        const int qrow = qt * 64 + wq + q * 4 + r;
        float smax = -3e38f;
#pragma unroll
        for (int ni = 0; ni < 4; ++ni) {
          float v = sf[ni][r] * sc_l2e;
          if (need_mask && (kv0 + ni * 16 + l > qrow)) v = -3e38f;
          sf[ni][r] = v;
          smax = fmaxf(smax, v);
        }
#pragma unroll
        for (int d = 1; d < 16; d <<= 1) smax = fmaxf(smax, __shfl_xor(smax, d));
        const float mnew = fmaxf(mrow[r], smax);
        const float alpha = exp2f(mrow[r] - mnew);
        mrow[r] = mnew;
        float rsum = 0.f;
#pragma unroll
        for (int ni = 0; ni < 4; ++ni) {
          float p = exp2f(sf[ni][r] - mnew);
          sf[ni][r] = p;
          rsum += p;
        }
#pragma unroll
        for (int d = 1; d < 16; d <<= 1) rsum += __shfl_xor(rsum, d);
        lrow[r] = lrow[r] * alpha + rsum;
#pragma unroll
        for (int di = 0; di < 8; ++di) o[di][r] *= alpha;
#pragma unroll
        for (int ni = 0; ni < 4; ++ni)   // C-layout -> LDS (A-layout source)
          Ps[wq + q * 4 + r][ni * 16 + l] = f2b(sf[ni][r]);
      }

      // ---- O += P V (Ps write->read same wave: DS in-order, no barrier) ----
#pragma unroll
      for (int kvk = 0; kvk < 2; ++kvk) {
        short8 pf = *(const short8*)&Ps[wq + l][kvk * 32 + q * 8];
#pragma unroll
        for (int di = 0; di < 8; ++di) {
          const int row = di * 16 + l;
          short8 vf = *(const short8*)&VTs[cur][row * 64 + (((kvk * 4 + q) ^ l7) * 8)];
          o[di] = __builtin_amdgcn_mfma_f32_16x16x32_bf16(pf, vf, o[di], 0, 0, 0);
        }
      }
      __syncthreads();   // prefetch DMA drained; all reads of cur done
    }

#pragma unroll
    for (int r = 0; r < 4; ++r) {
      const float inv = 1.0f / lrow[r];
      const int s = qt * 64 + wq + q * 4 + r;
      unsigned short* dst = attn + ((long)(b * SEQ + s)) * (NH * HD) + h * HD;
#pragma unroll
      for (int di = 0; di < 8; ++di)
        dst[di * 16 + l] = f2b(o[di][r] * inv);
    }
  }
}

// ---------------------------------------------------------------------------
extern "C" void kernel_launch(void* const* d_in, const int* in_sizes, int n_in,
                              void* d_out, int out_size, void* d_ws, size_t ws_size,
                              hipStream_t stream) {
  const float* x       = (const float*)d_in[0];   // [2,2048,2048]
  const float* w_qkv   = (const float*)d_in[1];   // [2048,3072]
  const float* w_dense = (const float*)d_in[2];   // [2048,2048]
  float* out = (float*)d_out;                     // [2,2048,2048] fp32

  char* ws = (char*)d_ws;
  const size_t MB = 1024 * 1024;
  unsigned short* xb    = (unsigned short*)(ws);            // 16 MB (aliased as attn later)
  unsigned short* wqkvT = (unsigned short*)(ws + 16 * MB);  // 12 MB
  unsigned short* wdT   = (unsigned short*)(ws + 28 * MB);  //  8 MB
  unsigned short* Qb    = (unsigned short*)(ws + 36 * MB);  // 16 MB
  unsigned short* Kb    = (unsigned short*)(ws + 52 * MB);  //  4 MB
  unsigned short* Vb    = (unsigned short*)(ws + 56 * MB);  //  4 MB
  unsigned short* VTb   = (unsigned short*)(ws + 60 * MB);  //  4 MB   (total 64 MB)
  unsigned short* attn  = xb;   // x no longer needed after qkv GEMM

  cvt_f32_bf16<<<(MROWS * EMB) / (256 * 4), 256, 0, stream>>>(x, xb, MROWS * EMB);
  transpose_cvt_f32<<<dim3(NQKV / 32, EMB / 32), 256, 0, stream>>>(w_qkv, wqkvT, EMB, NQKV);
  transpose_cvt_f32<<<dim3(EMB / 32, (NH * HD) / 32), 256, 0, stream>>>(w_dense, wdT, NH * HD, EMB);

  gemm_bt<0><<<dim3(NQKV / BN, MROWS / BM), 256, 0, stream>>>(
      xb, wqkvT, MROWS, NQKV, EMB, nullptr, Qb, Kb, Vb);

  rope_kernel<<<(NBATCH * NH * SEQ * 64) / 256, 256, 0, stream>>>(Qb);
  rope_kernel<<<(NBATCH * NKV * SEQ * 64) / 256, 256, 0, stream>>>(Kb);

  transpose_bf16<<<dim3(HD / 32, SEQ / 32, NBATCH * NKV), 256, 0, stream>>>(Vb, VTb, SEQ, HD);

  attn_kernel<<<dim3(16, NH, NBATCH), 256, 0, stream>>>(Qb, Kb, VTb, attn);

  gemm_bt<1><<<dim3(EMB / BN, MROWS / BM), 256, 0, stream>>>(
      attn, wdT, MROWS, EMB, NH * HD, out, nullptr, nullptr, nullptr);
}

// Round 4
// 329.335 us; speedup vs baseline: 1.3973x; 1.0218x over previous
//
#include <hip/hip_runtime.h>
#include <type_traits>

// ---------------------------------------------------------------------------
// MultiHeadAttention fused pipeline for MI355X (gfx950)
// x[B,S,E] @ w_qkv -> split QKV -> RoPE -> causal GQA flash attention -> @ w_dense
// B=2 S=2048 E=2048 H=16 KVH=4 D=128
// R4: attn VALU diet: Q pre-scaled (1/sqrt(d)*log2e folded into RoPE),
//     row-sum l via MFMA ones-columns (o[8]), saddr-form DMA offsets,
//     packed alpha rescale, compile-time masked-chunk split.
//     gemm MODE0: LDS-repack epilogue (overlaid smem, swizzled) + 16B stores.
// ---------------------------------------------------------------------------

typedef __attribute__((ext_vector_type(8))) short short8;
typedef __attribute__((ext_vector_type(4))) float floatx4;
typedef __attribute__((ext_vector_type(4))) unsigned short ushort4v;

constexpr int NH    = 16;
constexpr int NKV   = 4;
constexpr int HD    = 128;
constexpr int SEQ   = 2048;
constexpr int EMB   = 2048;
constexpr int NBATCH = 2;
constexpr int MROWS = NBATCH * SEQ;          // 4096
constexpr int NQKV  = (NH + 2 * NKV) * HD;   // 3072

__device__ __forceinline__ unsigned short f2b(float f) {
  union { float f; unsigned u; } v; v.f = f;
  unsigned u = v.u + 0x7FFFu + ((v.u >> 16) & 1u);   // RNE
  return (unsigned short)(u >> 16);
}
__device__ __forceinline__ float b2f(unsigned short h) {
  union { unsigned u; float f; } v; v.u = (unsigned)h << 16;
  return v.f;
}

// async global->LDS DMA, 16B per lane; lds dest = uniform base + lane*16
__device__ __forceinline__ void gload_lds16(const unsigned short* g,
                                            unsigned short* lds) {
  __builtin_amdgcn_global_load_lds(
      (const __attribute__((address_space(1))) unsigned int*)g,
      (__attribute__((address_space(3))) unsigned int*)lds, 16, 0, 0);
}

// --------------------------- fp32 -> bf16 cast ------------------------------
__global__ void cvt_f32_bf16(const float* __restrict__ in,
                             unsigned short* __restrict__ out, int n) {
  int i = (blockIdx.x * 256 + threadIdx.x) * 4;
  if (i + 3 < n) {
    floatx4 v = *(const floatx4*)(in + i);
    ushort4v o = { f2b(v[0]), f2b(v[1]), f2b(v[2]), f2b(v[3]) };
    *(ushort4v*)(out + i) = o;
  }
}

// -------------------- fp32 [R][C] -> bf16 [C][R] transpose ------------------
__global__ void transpose_cvt_f32(const float* __restrict__ in,
                                  unsigned short* __restrict__ out,
                                  int R, int C) {
  __shared__ float t[32][33];
  int c0 = blockIdx.x * 32, r0 = blockIdx.y * 32;
  int tx = threadIdx.x & 31, ty = threadIdx.x >> 5;  // ty 0..7
#pragma unroll
  for (int i = 0; i < 32; i += 8)
    t[ty + i][tx] = in[(long)(r0 + ty + i) * C + (c0 + tx)];
  __syncthreads();
#pragma unroll
  for (int i = 0; i < 32; i += 8)
    out[(long)(c0 + ty + i) * R + (r0 + tx)] = f2b(t[tx][ty + i]);
}

// -------------------- bf16 [R][C] -> bf16 [C][R] per-matrix -----------------
__global__ void transpose_bf16(const unsigned short* __restrict__ in,
                               unsigned short* __restrict__ out,
                               int R, int C) {
  __shared__ unsigned short t[32][34];
  long base = (long)blockIdx.z * R * C;
  in += base; out += base;
  int c0 = blockIdx.x * 32, r0 = blockIdx.y * 32;
  int tx = threadIdx.x & 31, ty = threadIdx.x >> 5;
#pragma unroll
  for (int i = 0; i < 32; i += 8)
    t[ty + i][tx] = in[(long)(r0 + ty + i) * C + (c0 + tx)];
  __syncthreads();
#pragma unroll
  for (int i = 0; i < 32; i += 8)
    out[(long)(c0 + ty + i) * R + (r0 + tx)] = t[tx][ty + i];
}

// ------------------------------- RoPE (in-place) ----------------------------
// scale: extra multiplier folded into the output (Q gets 1/sqrt(d)*log2e).
__global__ void rope_kernel(unsigned short* __restrict__ buf, float scale) {
  int idx = blockIdx.x * 256 + threadIdx.x;
  int i = idx & 63;
  int s = (idx >> 6) & (SEQ - 1);
  int bh = idx >> 17;                       // SEQ*64 = 1<<17
  unsigned short* p = buf + ((long)bh * SEQ + s) * HD;
  float e = -(float)i * (2.0f * 13.287712379549449f / 128.0f);
  float ang = (float)s * exp2f(e);
  float sn, c;
  sincosf(ang, &sn, &c);
  float x1 = b2f(p[i]), x2 = b2f(p[i + 64]);
  p[i]      = f2b((x1 * c - x2 * sn) * scale);
  p[i + 64] = f2b((x2 * c + x1 * sn) * scale);
}

// ------------------------------- GEMM (B^T) ---------------------------------
// C[M][N] = A[M][K](bf16) * BT[N][K](bf16)^T.  128x128 tile, 4 waves of 64x64.
// m97 structure: unpadded LDS, global_load_lds width-16 staging.
// MODE 0: LDS-repack epilogue -> vectorized bf16 stores into Q/K/V head-major
// MODE 1: fp32 dense store to outF (coalesced dwords).
constexpr int BM = 128, BN = 128, BK = 64;

template <int MODE>
__global__ __launch_bounds__(256, 2) void gemm_bt(
    const unsigned short* __restrict__ A,
    const unsigned short* __restrict__ BT,
    int Mdim, int Ndim, int Kdim,
    float* __restrict__ outF,
    unsigned short* __restrict__ Qb,
    unsigned short* __restrict__ Kb,
    unsigned short* __restrict__ Vb) {
  __shared__ __align__(16) unsigned short smem[BM * BK + BN * BK];  // 32 KB
  unsigned short (*As)[BK] = (unsigned short (*)[BK])smem;
  unsigned short (*Bs)[BK] = (unsigned short (*)[BK])(smem + BM * BK);
  const int tid = threadIdx.x;
  const int bm = blockIdx.y * BM;
  const int bn = blockIdx.x * BN;
  const int wave = tid >> 6, lane = tid & 63;
  const int l = lane & 15, q = lane >> 4;
  const int wm = (wave >> 1) * 64, wn = (wave & 1) * 64;

  floatx4 acc[4][4] = {};

  // DMA staging: one issue = 64 lanes x 16B = 1KB = 8 rows of 64 shorts.
  const int srow = lane >> 3;        // 0..7
  const int scol = (lane & 7) * 8;   // 0..56 shorts
  const unsigned short* Arow = A + (long)bm * Kdim;
  const unsigned short* Brow = BT + (long)bn * Kdim;

  for (int k0 = 0; k0 < Kdim; k0 += BK) {
#pragma unroll
    for (int i = 0; i < 4; ++i) {
      const int r0 = wave * 32 + i * 8;
      gload_lds16(Arow + (long)(r0 + srow) * Kdim + k0 + scol, &As[r0][0]);
      gload_lds16(Brow + (long)(r0 + srow) * Kdim + k0 + scol, &Bs[r0][0]);
    }
    __syncthreads();
#pragma unroll
    for (int kk = 0; kk < 2; ++kk) {
      short8 af[4], bfr[4];
#pragma unroll
      for (int mi = 0; mi < 4; ++mi)
        af[mi] = *(const short8*)&As[wm + mi * 16 + l][kk * 32 + q * 8];
#pragma unroll
      for (int ni = 0; ni < 4; ++ni)
        bfr[ni] = *(const short8*)&Bs[wn + ni * 16 + l][kk * 32 + q * 8];
#pragma unroll
      for (int mi = 0; mi < 4; ++mi)
#pragma unroll
        for (int ni = 0; ni < 4; ++ni)
          acc[mi][ni] = __builtin_amdgcn_mfma_f32_16x16x32_bf16(
              af[mi], bfr[ni], acc[mi][ni], 0, 0, 0);
    }
    __syncthreads();
  }

  if constexpr (MODE == 1) {
#pragma unroll
    for (int mi = 0; mi < 4; ++mi) {
      const int rowbase = bm + wm + mi * 16 + q * 4;
#pragma unroll
      for (int ni = 0; ni < 4; ++ni) {
        const int col = bn + wn + ni * 16 + l;
#pragma unroll
        for (int r = 0; r < 4; ++r)
          outF[(long)(rowbase + r) * Ndim + col] = acc[mi][ni][r];
      }
    }
  } else {
    // ---- repack through LDS (overlays As/Bs; safe after final barrier) ----
    // Ct[128][128] bf16, 16B-block col swizzle: blk_phys = blk ^ (row & 7).
    unsigned short (*Ct)[128] = (unsigned short (*)[128])smem;
#pragma unroll
    for (int mi = 0; mi < 4; ++mi)
#pragma unroll
      for (int ni = 0; ni < 4; ++ni)
#pragma unroll
        for (int r = 0; r < 4; ++r) {
          const int row = wm + mi * 16 + q * 4 + r;
          const int col = wn + ni * 16 + l;
          const int cs = ((((col >> 3) ^ row) & 7) | (col & 64 ? 8 : 0)) * 8 + (col & 7);
          Ct[row][cs] = f2b(acc[mi][ni][r]);
        }
    __syncthreads();
    // each thread: one row-half (64 cols = 8x16B), contiguous in dest (d-major)
    const int row = tid >> 1, g = tid & 1;
    const int m = bm + row, bb = m >> 11, s = m & (SEQ - 1);
    unsigned short* dst;
    if (bn < NH * HD)
      dst = Qb + (((long)(bb * NH + (bn >> 7))) * SEQ + s) * HD;
    else if (bn < (NH + NKV) * HD)
      dst = Kb + (((long)(bb * NKV + ((bn - NH * HD) >> 7))) * SEQ + s) * HD;
    else
      dst = Vb + (((long)(bb * NKV + ((bn - (NH + NKV) * HD) >> 7))) * SEQ + s) * HD;
#pragma unroll
    for (int i = 0; i < 8; ++i) {
      const int blk = (g * 8) + (i ^ (row & 7));
      *(short8*)(dst + g * 64 + i * 8) = *(const short8*)&Ct[row][blk * 8];
    }
  }
}

// --------------------------- flash attention --------------------------------
// q-tile = 64 rows (4 waves x 16 rows), paired (pair, 31-pair) -> uniform 33
// chunks/block. K/VT staged by async DMA (saddr + per-lane int offsets) into
// double-buffered XOR-swizzled LDS. VTs rows 128..143 = 1.0: PV's 9th
// accumulator o[8] carries the softmax denominator l with the same alpha
// recurrence as O (row-sum via MFMA).
__global__ __launch_bounds__(256, 2) void attn_kernel(
    const unsigned short* __restrict__ Q,   // [B][NH][S][D], pre-scaled
    const unsigned short* __restrict__ K,   // [B][NKV][S][D]
    const unsigned short* __restrict__ VT,  // [B][NKV][D][S]
    unsigned short* __restrict__ attn) {    // [B*S][NH*D]
  const int pair = blockIdx.x, h = blockIdx.y, b = blockIdx.z;
  const int kvh = h >> 2;   // jnp.repeat: q head h uses kv head h/4
  const int tid = threadIdx.x;
  const int wave = tid >> 6, lane = tid & 63;
  const int l = lane & 15, q = lane >> 4;
  const int l7 = l & 7;
  const int wq = wave * 16;

  const unsigned short* Kh = K + ((long)(b * NKV + kvh)) * SEQ * HD;
  const unsigned short* VTh = VT + ((long)(b * NKV + kvh)) * HD * SEQ;

  __shared__ __align__(16) unsigned short Ks[2][64 * 128];    // 32 KB swizzled
  __shared__ __align__(16) unsigned short VTs[2][144 * 64];   // 36 KB (+ones rows)
  __shared__ __align__(16) unsigned short Ps[64][72];         // 9 KB

  // per-lane DMA offsets (in shorts), computed once; base advances per chunk
  int koff[4], voff[4];
  {
    const int k_rl = lane >> 4, k_bp = lane & 15;
    const int v_rl = lane >> 3, v_bp = lane & 7;
#pragma unroll
    for (int j = 0; j < 4; ++j) {
      const int rk = (wave * 4 + j) * 4 + k_rl;
      koff[j] = rk * HD + (k_bp ^ (rk & 15)) * 8;
      const int rv = (wave * 4 + j) * 8 + v_rl;
      voff[j] = rv * SEQ + (v_bp ^ (rv & 7)) * 8;
    }
  }

  // ones rows 128..143 of both VT buffers (row-sum trick); 256 thr x 16B
  {
    short8 onesv;
#pragma unroll
    for (int i = 0; i < 8; ++i) onesv[i] = (short)0x3F80;
    const int t8 = tid * 8;
    unsigned short* dstp = (t8 < 1024) ? &VTs[0][128 * 64 + t8]
                                       : &VTs[1][128 * 64 + (t8 - 1024)];
    *(short8*)dstp = onesv;
  }

  auto stage = [&](int c, int buf) {
    const unsigned short* kc = Kh + c * (64 * HD);
    const unsigned short* vc = VTh + c * 64;
#pragma unroll
    for (int j = 0; j < 4; ++j)
      gload_lds16(kc + koff[j], &Ks[buf][(wave * 4 + j) * 4 * 128]);
#pragma unroll
    for (int j = 0; j < 4; ++j)
      gload_lds16(vc + voff[j], &VTs[buf][(wave * 4 + j) * 8 * 64]);
  };

  auto chunk_body = [&](auto masked, int cur, int kv0, int qt,
                        short8* qf, floatx4* o, float* mrow) {
    constexpr bool MASKED = decltype(masked)::value;
    // ---- S = Q K^T (16q x 64kv per wave), Q pre-scaled ----
    floatx4 sf[4] = {};
#pragma unroll
    for (int kk = 0; kk < 4; ++kk) {
      short8 kf[4];
#pragma unroll
      for (int ni = 0; ni < 4; ++ni) {
        const int row = ni * 16 + l;
        kf[ni] = *(const short8*)&Ks[cur][row * 128 + (((kk * 4 + q) ^ l) * 8)];
      }
#pragma unroll
      for (int ni = 0; ni < 4; ++ni)
        sf[ni] = __builtin_amdgcn_mfma_f32_16x16x32_bf16(
            qf[kk], kf[ni], sf[ni], 0, 0, 0);
    }
    // ---- online max + alpha ----
    float alpha[4], mloc[4];
#pragma unroll
    for (int r = 0; r < 4; ++r) {
      if constexpr (MASKED) {
        const int qrow = qt * 64 + wq + q * 4 + r;
#pragma unroll
        for (int ni = 0; ni < 4; ++ni)
          if (kv0 + ni * 16 + l > qrow) sf[ni][r] = -3e38f;
      }
      float smax = fmaxf(fmaxf(sf[0][r], sf[1][r]), fmaxf(sf[2][r], sf[3][r]));
#pragma unroll
      for (int d = 1; d < 16; d <<= 1) smax = fmaxf(smax, __shfl_xor(smax, d));
      const float mnew = fmaxf(mrow[r], smax);
      alpha[r] = exp2f(mrow[r] - mnew);
      mrow[r] = mnew;
      mloc[r] = mnew;
    }
    floatx4 av = { alpha[0], alpha[1], alpha[2], alpha[3] };
#pragma unroll
    for (int di = 0; di < 9; ++di) o[di] *= av;   // includes l (o[8])
    // ---- P = exp2(S - m) -> LDS (C-layout -> A-layout) ----
#pragma unroll
    for (int r = 0; r < 4; ++r)
#pragma unroll
      for (int ni = 0; ni < 4; ++ni)
        Ps[wq + q * 4 + r][ni * 16 + l] = f2b(exp2f(sf[ni][r] - mloc[r]));
    // ---- O += P V ; o[8] += P * 1 (row sum) ----
#pragma unroll
    for (int kvk = 0; kvk < 2; ++kvk) {
      short8 pf = *(const short8*)&Ps[wq + l][kvk * 32 + q * 8];
#pragma unroll
      for (int di = 0; di < 9; ++di) {
        const int row = di * 16 + l;
        short8 vf = *(const short8*)&VTs[cur][row * 64 + (((kvk * 4 + q) ^ l7) * 8)];
        o[di] = __builtin_amdgcn_mfma_f32_16x16x32_bf16(pf, vf, o[di], 0, 0, 0);
      }
    }
  };

#pragma unroll 1
  for (int half = 0; half < 2; ++half) {
    const int qt = half ? (31 - pair) : pair;
    const unsigned short* Qh = Q + (((long)(b * NH + h)) * SEQ + qt * 64) * HD;

    short8 qf[4];
#pragma unroll
    for (int kk = 0; kk < 4; ++kk)
      qf[kk] = *(const short8*)(Qh + (long)(wq + l) * HD + kk * 32 + q * 8);

    floatx4 o[9] = {};
    float mrow[4];
#pragma unroll
    for (int r = 0; r < 4; ++r) mrow[r] = -3e38f;

    const int nchunk = qt + 1;   // causal, Tk=64

    stage(0, 0);
    __syncthreads();

    int c = 0;
#pragma unroll 1
    for (; c < nchunk - 1; ++c) {
      stage(c + 1, (c & 1) ^ 1);
      chunk_body(std::false_type{}, c & 1, c * 64, qt, qf, o, mrow);
      __syncthreads();   // prefetch DMA drained; all reads of cur done
    }
    chunk_body(std::true_type{}, c & 1, c * 64, qt, qf, o, mrow);
    __syncthreads();     // protect buffers before next half restages

#pragma unroll
    for (int r = 0; r < 4; ++r) {
      const float inv = 1.0f / o[8][r];   // l (same in every lane)
      const int s = qt * 64 + wq + q * 4 + r;
      unsigned short* dst = attn + ((long)(b * SEQ + s)) * (NH * HD) + h * HD;
#pragma unroll
      for (int di = 0; di < 8; ++di)
        dst[di * 16 + l] = f2b(o[di][r] * inv);
    }
  }
}

// ---------------------------------------------------------------------------
extern "C" void kernel_launch(void* const* d_in, const int* in_sizes, int n_in,
                              void* d_out, int out_size, void* d_ws, size_t ws_size,
                              hipStream_t stream) {
  const float* x       = (const float*)d_in[0];   // [2,2048,2048]
  const float* w_qkv   = (const float*)d_in[1];   // [2048,3072]
  const float* w_dense = (const float*)d_in[2];   // [2048,2048]
  float* out = (float*)d_out;                     // [2,2048,2048] fp32

  char* ws = (char*)d_ws;
  const size_t MB = 1024 * 1024;
  unsigned short* xb    = (unsigned short*)(ws);            // 16 MB (aliased as attn later)
  unsigned short* wqkvT = (unsigned short*)(ws + 16 * MB);  // 12 MB
  unsigned short* wdT   = (unsigned short*)(ws + 28 * MB);  //  8 MB
  unsigned short* Qb    = (unsigned short*)(ws + 36 * MB);  // 16 MB
  unsigned short* Kb    = (unsigned short*)(ws + 52 * MB);  //  4 MB
  unsigned short* Vb    = (unsigned short*)(ws + 56 * MB);  //  4 MB
  unsigned short* VTb   = (unsigned short*)(ws + 60 * MB);  //  4 MB   (total 64 MB)
  unsigned short* attn  = xb;   // x no longer needed after qkv GEMM

  const float qscale = 0.08838834764831845f * 1.4426950408889634f; // 1/sqrt(128)*log2e

  cvt_f32_bf16<<<(MROWS * EMB) / (256 * 4), 256, 0, stream>>>(x, xb, MROWS * EMB);
  transpose_cvt_f32<<<dim3(NQKV / 32, EMB / 32), 256, 0, stream>>>(w_qkv, wqkvT, EMB, NQKV);
  transpose_cvt_f32<<<dim3(EMB / 32, (NH * HD) / 32), 256, 0, stream>>>(w_dense, wdT, NH * HD, EMB);

  gemm_bt<0><<<dim3(NQKV / BN, MROWS / BM), 256, 0, stream>>>(
      xb, wqkvT, MROWS, NQKV, EMB, nullptr, Qb, Kb, Vb);

  rope_kernel<<<(NBATCH * NH * SEQ * 64) / 256, 256, 0, stream>>>(Qb, qscale);
  rope_kernel<<<(NBATCH * NKV * SEQ * 64) / 256, 256, 0, stream>>>(Kb, 1.0f);

  transpose_bf16<<<dim3(HD / 32, SEQ / 32, NBATCH * NKV), 256, 0, stream>>>(Vb, VTb, SEQ, HD);

  attn_kernel<<<dim3(16, NH, NBATCH), 256, 0, stream>>>(Qb, Kb, VTb, attn);

  gemm_bt<1><<<dim3(EMB / BN, MROWS / BM), 256, 0, stream>>>(
      attn, wdT, MROWS, EMB, NH * HD, out, nullptr, nullptr, nullptr);
}